// Round 14
// baseline (140.132 us; speedup 1.0000x reference)
//
#include <hip/hip_runtime.h>
#include <math.h>

#define BTOT   32768
#define NNODE  78
#define NEMB   30
#define NPROJ  10
#define NGR    7
#define ROW    (NNODE*NEMB)       // 2340 floats per batch
#define BPW    8                  // batches per WG (512 thr, 8 waves, 2 roles)
#define FEAT_OUT (BTOT*NGR*NEMB)
#define NWG    (BTOT/BPW)         // 4096
#define APITCH 80                 // attpart row pitch (floats)

__constant__ int d_off[NGR] = {0,5,14,23,48,57,66};
__constant__ int d_len[NGR] = {5,9,9,25,9,9,12};

// ---- cross-lane allreduce: 4 DPP steps (VALU) + ds_swizzle xor16 ----
template<int CTRL>
__device__ __forceinline__ float dpp_f(float x) {
  return __int_as_float(__builtin_amdgcn_update_dpp(0, __float_as_int(x), CTRL, 0xF, 0xF, true));
}
__device__ __forceinline__ float swz16(float x) {
  return __int_as_float(__builtin_amdgcn_ds_swizzle(__float_as_int(x), 0x401F));
}
__device__ __forceinline__ float hsum32(float x) {
  x += dpp_f<0xB1>(x);    // quad_perm xor1
  x += dpp_f<0x4E>(x);    // quad_perm xor2
  x += dpp_f<0x141>(x);   // row_half_mirror
  x += dpp_f<0x140>(x);   // row_mirror
  x += swz16(x);          // xor16
  return x;
}

// ---- validated R12 pieces: load burst / compute body ----
template<int LEN>
__device__ __forceinline__ void load_rows(const float* __restrict__ xsub,
                                          float (&xr)[LEN], int e) {
#pragma unroll
  for (int j = 0; j < LEN; ++j) xr[j] = xsub[j * NEMB + e];  // 120B/row
}

template<int OFF, int LEN, int G>
__device__ __forceinline__ void compute_graph(
    const float (&xr)[LEN], const float (&Wr)[NPROJ],
    float* __restrict__ arow, float* __restrict__ outb,
    int lane31, bool evalid, int e)
{
  float xsum = 0.f;
#pragma unroll
  for (int j = 0; j < LEN; ++j) xsum += xr[j];
  float t[NPROJ];
#pragma unroll
  for (int h = 0; h < NPROJ; ++h) t[h] = hsum32(Wr[h] * xsum);
  float u = 0.f;
#pragma unroll
  for (int h = 0; h < NPROJ; ++h) u = fmaf(Wr[h], t[h], u);
  float lg[LEN];
#pragma unroll
  for (int j = 0; j < LEN; ++j) lg[j] = hsum32(xr[j] * u);
  float m = lg[0];
#pragma unroll
  for (int j = 1; j < LEN; ++j) m = fmaxf(m, lg[j]);
  float s = 0.f;
#pragma unroll
  for (int j = 0; j < LEN; ++j) { lg[j] = __expf(lg[j] - m); s += lg[j]; }
  float inv = 1.f / s;
  float f = 0.f, myatt = 0.f;
#pragma unroll
  for (int j = 0; j < LEN; ++j) {
    float a = lg[j] * inv;
    f = fmaf(a, xr[j], f);
    if (lane31 == j) myatt = a;
  }
  if (evalid) outb[G * NEMB + e] = f;            // 120B contiguous store
  if (lane31 < LEN) arow[OFF + lane31] = myatt;
}

__global__ __launch_bounds__(512) void meso_main(
    const float* __restrict__ x, const float* __restrict__ wt,
    float* __restrict__ out, float* __restrict__ attpart)
{
  __shared__ float att_all[BPW][NNODE];   // 2.4 KB

  const int tid    = threadIdx.x;
  const int slot   = tid >> 5;        // 0..15 half-wave slot
  const int half   = slot & 7;        // batch slot 0..7
  const int role   = slot >> 3;       // 0: graphs {0,1,2,6}; 1: graphs {3,4,5}
  const int lane31 = tid & 31;
  const bool evalid = lane31 < NEMB;
  const int e = evalid ? lane31 : (NEMB - 1);

  float Wr[NPROJ];
#pragma unroll
  for (int h = 0; h < NPROJ; ++h) Wr[h] = evalid ? wt[e * NPROJ + h] : 0.f;

  const long long b = (long long)blockIdx.x * BPW + half;
  const float* xrow = x + b * ROW;
  float* outb = out + b * (NGR * NEMB);
  float* arow = att_all[half];

  if (role == 0) {
    // role A: 35 rows, 4 short graphs; all loads issued up front (max in flight)
    float xr0[5], xr1[9], xr2[9], xr6[12];
    load_rows< 5>(xrow +  0*NEMB, xr0, e);
    load_rows< 9>(xrow +  5*NEMB, xr1, e);
    load_rows< 9>(xrow + 14*NEMB, xr2, e);
    load_rows<12>(xrow + 66*NEMB, xr6, e);
    compute_graph< 0, 5,0>(xr0, Wr, arow, outb, lane31, evalid, e);
    compute_graph< 5, 9,1>(xr1, Wr, arow, outb, lane31, evalid, e);
    compute_graph<14, 9,2>(xr2, Wr, arow, outb, lane31, evalid, e);
    compute_graph<66,12,6>(xr6, Wr, arow, outb, lane31, evalid, e);
  } else {
    // role B: 43 rows, pipeline one-ahead to cap VGPR (xr3[25]+lg[25] is the peak)
    float xr3[25], xr4[9], xr5[9];
    load_rows<25>(xrow + 23*NEMB, xr3, e);
    load_rows< 9>(xrow + 48*NEMB, xr4, e);
    compute_graph<23,25,3>(xr3, Wr, arow, outb, lane31, evalid, e);
    load_rows< 9>(xrow + 57*NEMB, xr5, e);
    compute_graph<48, 9,4>(xr4, Wr, arow, outb, lane31, evalid, e);
    compute_graph<57, 9,5>(xr5, Wr, arow, outb, lane31, evalid, e);
  }

  __syncthreads();
  // per-WG att sum -> plain coalesced store (no atomics, no init kernel)
  if (tid < NNODE) {
    float s = 0.f;
#pragma unroll
    for (int h = 0; h < BPW; ++h) s += att_all[h][tid];
    attpart[(size_t)blockIdx.x * APITCH + tid] = s;
  }
}

// 21 WGs: one per (graph, axis) output; reduce 4096 WG-partials.
__global__ __launch_bounds__(256) void meso_coor(
    const float* __restrict__ attpart,
    const float* __restrict__ coords,
    float* __restrict__ out_coor)
{
  __shared__ float red[256];
  const int t  = blockIdx.x;            // 0..20
  const int g  = t / 3, kk = t % 3;
  const int off = d_off[g], len = d_len[g];
  const int tid = threadIdx.x;

  float partial = 0.f;
  for (int j = 0; j < len; ++j) {
    float c = coords[(off+j)*3 + kk];
    float s = 0.f;
    for (int w = tid; w < NWG; w += 256)
      s += attpart[(size_t)w * APITCH + off + j];
    partial = fmaf(c, s, partial);
  }
  red[tid] = partial;
  __syncthreads();
#pragma unroll
  for (int k = 128; k > 0; k >>= 1) {
    if (tid < k) red[tid] += red[tid + k];
    __syncthreads();
  }
  if (tid == 0) out_coor[t] = red[0] * (1.0f/(float)BTOT);
}

extern "C" void kernel_launch(void* const* d_in, const int* in_sizes, int n_in,
                              void* d_out, int out_size, void* d_ws, size_t ws_size,
                              hipStream_t stream) {
  const float* x      = (const float*)d_in[0];
  const float* coords = (const float*)d_in[1];
  const float* wt     = (const float*)d_in[2];
  float* out     = (float*)d_out;
  float* attpart = (float*)d_ws;   // 4096*80*4 = 1.31 MB, fully overwritten each call

  meso_main<<<NWG, 512, 0, stream>>>(x, wt, out, attpart);
  meso_coor<<<21, 256, 0, stream>>>(attpart, coords, out + FEAT_OUT);
}

// Round 15
// 82.275 us; speedup vs baseline: 1.7032x; 1.7032x over previous
//
#include <hip/hip_runtime.h>
#include <math.h>

#define BTOT   32768
#define NNODE  78
#define NEMB   30
#define NPROJ  10
#define NGR    7
#define ROW    (NNODE*NEMB)       // 2340 floats per batch
#define BPW    8                  // batches per WG (8 half-waves, 256 thr)
#define FEAT_OUT (BTOT*NGR*NEMB)
#define NSLOT  64                 // atomic contention spread (R7-proven)
#define SLOTP  80                 // padded stride per slot (floats)

__constant__ int d_off[NGR] = {0,5,14,23,48,57,66};
__constant__ int d_len[NGR] = {5,9,9,25,9,9,12};

// ---- cross-lane allreduce: 4 DPP steps (VALU) + ds_swizzle xor16 ----
template<int CTRL>
__device__ __forceinline__ float dpp_f(float x) {
  return __int_as_float(__builtin_amdgcn_update_dpp(0, __float_as_int(x), CTRL, 0xF, 0xF, true));
}
__device__ __forceinline__ float swz16(float x) {
  return __int_as_float(__builtin_amdgcn_ds_swizzle(__float_as_int(x), 0x401F));
}
__device__ __forceinline__ float hsum32(float x) {
  x += dpp_f<0xB1>(x);    // quad_perm xor1
  x += dpp_f<0x4E>(x);    // quad_perm xor2
  x += dpp_f<0x141>(x);   // row_half_mirror
  x += dpp_f<0x140>(x);   // row_mirror
  x += swz16(x);          // xor16
  return x;
}

// Small-graph body (R7-validated): loads inside, xr/lg registers.
template<int OFF, int LEN, int G>
__device__ __forceinline__ void process_graph(
    const float* __restrict__ xrow, const float (&Wr)[NPROJ],
    float* __restrict__ arow, float* __restrict__ outb,
    int lane31, bool evalid, int e)
{
  float xr[LEN];
  float xsum = 0.f;
#pragma unroll
  for (int j = 0; j < LEN; ++j) {
    xr[j] = xrow[(OFF + j) * NEMB + e];
    xsum += xr[j];
  }
  float t[NPROJ];
#pragma unroll
  for (int h = 0; h < NPROJ; ++h) t[h] = hsum32(Wr[h] * xsum);
  float u = 0.f;
#pragma unroll
  for (int h = 0; h < NPROJ; ++h) u = fmaf(Wr[h], t[h], u);
  float lg[LEN];
#pragma unroll
  for (int j = 0; j < LEN; ++j) lg[j] = hsum32(xr[j] * u);
  float m = lg[0];
#pragma unroll
  for (int j = 1; j < LEN; ++j) m = fmaxf(m, lg[j]);
  float s = 0.f;
#pragma unroll
  for (int j = 0; j < LEN; ++j) { lg[j] = __expf(lg[j] - m); s += lg[j]; }
  float inv = 1.f / s;
  float f = 0.f, myatt = 0.f;
#pragma unroll
  for (int j = 0; j < LEN; ++j) {
    float a = lg[j] * inv;
    f = fmaf(a, xr[j], f);
    if (lane31 == j) myatt = a;
  }
  if (evalid) outb[G * NEMB + e] = f;
  if (lane31 < LEN) arow[OFF + lane31] = myatt;
}

// g3 (LEN=25) chunked 13+12 with online-softmax merge: halves register peak
// (xr[25]+lg[25] -> max 38 live). exp values parked raw in LDS, rescaled after merge.
__device__ __forceinline__ void process_g3_chunked(
    const float* __restrict__ xrow, const float (&Wr)[NPROJ],
    float* __restrict__ arow, float* __restrict__ outb,
    int lane31, bool evalid, int e)
{
  constexpr int OFF = 23, LA = 13, LB = 12;
  // load both chunks up front (25 loads in flight), xsum over all rows
  float xrA[LA], xrB[LB];
  float xsum = 0.f;
#pragma unroll
  for (int j = 0; j < LA; ++j) { xrA[j] = xrow[(OFF+j)*NEMB + e];     xsum += xrA[j]; }
#pragma unroll
  for (int j = 0; j < LB; ++j) { xrB[j] = xrow[(OFF+LA+j)*NEMB + e];  xsum += xrB[j]; }
  float t[NPROJ];
#pragma unroll
  for (int h = 0; h < NPROJ; ++h) t[h] = hsum32(Wr[h] * xsum);
  float u = 0.f;
#pragma unroll
  for (int h = 0; h < NPROJ; ++h) u = fmaf(Wr[h], t[h], u);

  // ---- chunk A: logits, local softmax stats, raw-exp park, partial feat ----
  float lgA[LA];
#pragma unroll
  for (int j = 0; j < LA; ++j) lgA[j] = hsum32(xrA[j] * u);
  float mA = lgA[0];
#pragma unroll
  for (int j = 1; j < LA; ++j) mA = fmaxf(mA, lgA[j]);
  float sA = 0.f, fA = 0.f, myexpA = 0.f;
#pragma unroll
  for (int j = 0; j < LA; ++j) {
    float ex = __expf(lgA[j] - mA);
    sA += ex;
    fA = fmaf(ex, xrA[j], fA);
    if (lane31 == j) myexpA = ex;
  }
  if (lane31 < LA) arow[OFF + lane31] = myexpA;      // raw park, rescaled below
  // xrA, lgA dead here -> registers reused for chunk B

  // ---- chunk B ----
  float lgB[LB];
#pragma unroll
  for (int j = 0; j < LB; ++j) lgB[j] = hsum32(xrB[j] * u);
  float mB = lgB[0];
#pragma unroll
  for (int j = 1; j < LB; ++j) mB = fmaxf(mB, lgB[j]);
  float sB = 0.f, fB = 0.f, myexpB = 0.f;
#pragma unroll
  for (int j = 0; j < LB; ++j) {
    float ex = __expf(lgB[j] - mB);
    sB += ex;
    fB = fmaf(ex, xrB[j], fB);
    if (lane31 == j) myexpB = ex;
  }
  if (lane31 < LB) arow[OFF + LA + lane31] = myexpB; // raw park

  // ---- online merge ----
  float m  = fmaxf(mA, mB);
  float cA = __expf(mA - m), cB = __expf(mB - m);
  float inv = 1.f / (sA * cA + sB * cB);
  float f = (fA * cA + fB * cB) * inv;
  if (evalid) outb[3 * NEMB + e] = f;
  // rescale parked exps to final att (per-lane in-order LDS RMW)
  if (lane31 < LA) arow[OFF + lane31]      *= cA * inv;
  if (lane31 < LB) arow[OFF + LA + lane31] *= cB * inv;
}

__global__ __launch_bounds__(256) void meso_main(
    const float* __restrict__ x, const float* __restrict__ wt,
    float* __restrict__ out, float* __restrict__ attpart)
{
  __shared__ float att_all[BPW][NNODE];   // 2.4 KB

  const int tid    = threadIdx.x;
  const int half   = tid >> 5;
  const int lane31 = tid & 31;
  const bool evalid = lane31 < NEMB;
  const int e = evalid ? lane31 : (NEMB - 1);

  float Wr[NPROJ];
#pragma unroll
  for (int h = 0; h < NPROJ; ++h) Wr[h] = evalid ? wt[e * NPROJ + h] : 0.f;

  const long long b = (long long)blockIdx.x * BPW + half;
  const float* xrow = x + b * ROW;
  float* outb = out + b * (NGR * NEMB);
  float* arow = att_all[half];

  process_graph< 0, 5,0>(xrow, Wr, arow, outb, lane31, evalid, e);
  process_graph< 5, 9,1>(xrow, Wr, arow, outb, lane31, evalid, e);
  process_graph<14, 9,2>(xrow, Wr, arow, outb, lane31, evalid, e);
  process_g3_chunked    (xrow, Wr, arow, outb, lane31, evalid, e);
  process_graph<48, 9,4>(xrow, Wr, arow, outb, lane31, evalid, e);
  process_graph<57, 9,5>(xrow, Wr, arow, outb, lane31, evalid, e);
  process_graph<66,12,6>(xrow, Wr, arow, outb, lane31, evalid, e);

  __syncthreads();
  // 64-way contention spread (R7-proven output path)
  if (tid < NNODE) {
    float s = 0.f;
#pragma unroll
    for (int h = 0; h < BPW; ++h) s += att_all[h][tid];
    atomicAdd(&attpart[(blockIdx.x & (NSLOT-1)) * SLOTP + tid], s);
  }
}

__global__ __launch_bounds__(128) void meso_coor(
    const float* __restrict__ attpart,
    const float* __restrict__ coords,
    float* __restrict__ out_coor)
{
  __shared__ float asum[NNODE];
  int t = threadIdx.x;
  if (t < NNODE) {
    float s = 0.f;
#pragma unroll
    for (int k = 0; k < NSLOT; ++k) s += attpart[k * SLOTP + t];
    asum[t] = s;
  }
  __syncthreads();
  if (t < NGR*3) {
    int g = t / 3, kk = t % 3;
    int off = d_off[g], len = d_len[g];
    float s = 0.f;
    for (int j = 0; j < len; ++j) s += asum[off+j] * coords[(off+j)*3 + kk];
    out_coor[t] = s * (1.0f/(float)BTOT);
  }
}

extern "C" void kernel_launch(void* const* d_in, const int* in_sizes, int n_in,
                              void* d_out, int out_size, void* d_ws, size_t ws_size,
                              hipStream_t stream) {
  const float* x      = (const float*)d_in[0];
  const float* coords = (const float*)d_in[1];
  const float* wt     = (const float*)d_in[2];
  float* out     = (float*)d_out;
  float* attpart = (float*)d_ws;

  hipMemsetAsync(attpart, 0, NSLOT * SLOTP * sizeof(float), stream);
  meso_main<<<BTOT/BPW, 256, 0, stream>>>(x, wt, out, attpart);
  meso_coor<<<1, 128, 0, stream>>>(attpart, coords, out + FEAT_OUT);
}